// Round 2
// baseline (312.773 us; speedup 1.0000x reference)
//
#include <hip/hip_runtime.h>
#include <stdint.h>

// ---- problem dims (fixed by reference setup_inputs) ----
#define NB      4
#define N_LIDAR 16384
#define N_IMG   4096
#define N_TOT   20480          // N_LIDAR + N_IMG
#define N_PAD   32768          // next pow2 for bitonic sort
#define NC      256
#define NVIEWS  6
#define MULTK   100000LL

// d_out layout (all float32):
//   [0, TOK_END)                 sorted_tokens  [B,N,C]
//   [TOK_END, IDX_END)           idx (as float)
//   [IDX_END, MSK_END)           sorted_mask (0/1 float)
//   [MSK_END], [MSK_END+1]       16384.0f, 1.0f
#define TOK_END ((size_t)NB * N_TOT * NC)
#define IDX_END (TOK_END + (size_t)NB * N_TOT)
#define MSK_END (IDX_END + (size_t)NB * N_TOT)

// ---- workspace layout ----
#define WS_COMPS_OFF 0                                    // NB*N_PAD u64 (1 MiB)
#define WS_QBUF_OFF  ((size_t)NB * N_PAD * 8)             // NB*N_TOT int4
#define WS_MM_OFF    (WS_QBUF_OFF + (size_t)NB * N_TOT * 16)  // 24 ints

__global__ void init_mm_kernel(int* mm) {
    int t = threadIdx.x;
    if (t < 12) mm[t] = 0x7FFFFFFF;           // mins
    else if (t < 24) mm[t] = (int)0x80000000; // maxes
}

// one thread per point: quantize, wave-reduce min/max, one atomic set per wave
__global__ __launch_bounds__(256) void quant_kernel(
    const float* __restrict__ lidar_coords,
    const float* __restrict__ kuvd,
    const float* __restrict__ Kmat,
    const float* __restrict__ Tmat,
    const float* __restrict__ postR,
    const float* __restrict__ postT,
    int4* __restrict__ qbuf, int* __restrict__ mm)
{
    int gid = blockIdx.x * blockDim.x + threadIdx.x;   // exactly NB*N_TOT threads
    int b = gid / N_TOT, i = gid - b * N_TOT;
    int q0, q1, q2;
    if (i < N_LIDAR) {
        const float* c = lidar_coords + ((size_t)b * N_LIDAR + i) * 3;
        q0 = (int)floorf(c[0]);
        q1 = (int)floorf(c[1]);
        q2 = (int)floorf(c[2]);
    } else {
        int ii = i - N_LIDAR;
        const float* kv = kuvd + ((size_t)b * N_IMG + ii) * 4;
        int cam = (int)kv[0];
        double u = kv[1], v = kv[2], D = kv[3];
        const float* R  = postR + ((size_t)b * NVIEWS + cam) * 9;
        const float* t  = postT + ((size_t)b * NVIEWS + cam) * 3;
        const float* Km = Kmat  + ((size_t)b * NVIEWS + cam) * 9;
        const float* T  = Tmat  + ((size_t)b * NVIEWS + cam) * 16;
        double x0 = u - (double)t[0];
        double x1 = v - (double)t[1];
        double x2 = 1.0 - (double)t[2];
        // inverse of post_rot (3x3) via adjugate, f64
        double r00=R[0], r01=R[1], r02=R[2];
        double r10=R[3], r11=R[4], r12=R[5];
        double r20=R[6], r21=R[7], r22=R[8];
        double c00 = r11*r22 - r12*r21;
        double c01 = r02*r21 - r01*r22;
        double c02 = r01*r12 - r02*r11;
        double c10 = r12*r20 - r10*r22;
        double c11 = r00*r22 - r02*r20;
        double c12 = r02*r10 - r00*r12;
        double det = r00*(r11*r22 - r12*r21)
                   - r01*(r10*r22 - r12*r20)
                   + r02*(r10*r21 - r11*r20);
        double inv = 1.0 / det;
        double w0 = (c00*x0 + c01*x1 + c02*x2) * inv;
        double w1 = (c10*x0 + c11*x1 + c12*x2) * inv;
        double fx = Km[0], cx = Km[2], fy = Km[4], cy = Km[5];
        double camx = (w0 - cx) / fx * D;
        double camy = (w1 - cy) / fy * D;
        double camz = D;
        double wx = (double)T[0]*camx + (double)T[1]*camy + (double)T[2]*camz  + (double)T[3];
        double wy = (double)T[4]*camx + (double)T[5]*camy + (double)T[6]*camz  + (double)T[7];
        double wz = (double)T[8]*camx + (double)T[9]*camy + (double)T[10]*camz + (double)T[11];
        q0 = (int)floor(wx);
        q1 = (int)floor(wy);
        q2 = (int)floor(wz);
    }
    qbuf[gid] = make_int4(q0, q1, q2, 0);

    // wave-level pre-reduction (20480 % 64 == 0 so waves never straddle batches)
    int mn0=q0, mx0=q0, mn1=q1, mx1=q1, mn2=q2, mx2=q2;
    #pragma unroll
    for (int off = 32; off; off >>= 1) {
        mn0 = min(mn0, __shfl_xor(mn0, off));
        mx0 = max(mx0, __shfl_xor(mx0, off));
        mn1 = min(mn1, __shfl_xor(mn1, off));
        mx1 = max(mx1, __shfl_xor(mx1, off));
        mn2 = min(mn2, __shfl_xor(mn2, off));
        mx2 = max(mx2, __shfl_xor(mx2, off));
    }
    if ((threadIdx.x & 63) == 0) {
        atomicMin(&mm[b*3+0], mn0); atomicMax(&mm[12 + b*3+0], mx0);
        atomicMin(&mm[b*3+1], mn1); atomicMax(&mm[12 + b*3+1], mx1);
        atomicMin(&mm[b*3+2], mn2); atomicMax(&mm[12 + b*3+2], mx2);
    }
}

// sortable composite: (key << 16) | original_index ; padding = all-ones.
// Ascending sort of composites == stable argsort of keys (real keys < 2^42).
__device__ inline unsigned long long make_comp(
    int b, int i, const int4* __restrict__ qbuf, const int* __restrict__ mm,
    const unsigned char* __restrict__ lmask, const unsigned char* __restrict__ imask)
{
    if (i >= N_TOT) return ~0ull;
    int4 q = qbuf[b * N_TOT + i];
    int mn0 = mm[b*3+0], mn1 = mm[b*3+1], mn2 = mm[b*3+2];
    int d0 = q.x - mn0, d1 = q.y - mn1, d2 = q.z - mn2;
    int max1 = mm[12 + b*3+1] - mn1;
    int max2 = mm[12 + b*3+2] - mn2;
    long long s1 = (d0 & 1) ? (long long)(max1 - d1) : (long long)d1;
    long long s2 = ((d0 + d1) & 1) ? (long long)(max2 - d2) : (long long)d2;
    long long key = (long long)d0 * (MULTK * MULTK) + s1 * MULTK + s2;
    bool m = (i < N_LIDAR) ? (lmask[b * N_LIDAR + i] != 0)
                           : (imask[b * N_IMG + (i - N_LIDAR)] != 0);
    if (m) key = (1LL << 45);   // after every real key; stable among masked
    return ((unsigned long long)key << 16) | (unsigned)i;
}

// full local bitonic sort of a 4096-element segment (key build fused in)
__global__ __launch_bounds__(512) void sort_local_full_kernel(
    const int4* __restrict__ qbuf, const int* __restrict__ mm,
    const unsigned char* __restrict__ lmask, const unsigned char* __restrict__ imask,
    unsigned long long* __restrict__ comps)
{
    __shared__ unsigned long long smem[4096];   // 32 KiB
    int blk = blockIdx.x;                       // 32 blocks
    int b = blk >> 3, bb = blk & 7;
    int base = bb * 4096;
    int t = threadIdx.x;
    #pragma unroll
    for (int s = 0; s < 8; ++s) {
        int i = t + s * 512;
        smem[i] = make_comp(b, base + i, qbuf, mm, lmask, imask);
    }
    __syncthreads();
    for (int k = 2; k <= 4096; k <<= 1) {
        for (int j = k >> 1; j > 0; j >>= 1) {
            #pragma unroll
            for (int pp = 0; pp < 4; ++pp) {
                int p = t + pp * 512;                       // pair idx [0,2048)
                int i = ((p & ~(j-1)) << 1) | (p & (j-1));
                int l = i | j;
                bool up = (((base + i) & k) == 0);          // direction from segment-global idx
                unsigned long long a = smem[i], c = smem[l];
                if ((a > c) == up) { smem[i] = c; smem[l] = a; }
            }
            __syncthreads();
        }
    }
    unsigned long long* seg = comps + ((size_t)b << 15) + base;
    #pragma unroll
    for (int s = 0; s < 8; ++s) { int i = t + s*512; seg[i] = smem[i]; }
}

// local merge: j = 2048 .. 1 for a given k-phase
__global__ __launch_bounds__(512) void sort_local_merge_kernel(
    unsigned long long* __restrict__ comps, int k)
{
    __shared__ unsigned long long smem[4096];
    int blk = blockIdx.x;
    int b = blk >> 3, bb = blk & 7;
    int base = bb * 4096;
    int t = threadIdx.x;
    unsigned long long* seg = comps + ((size_t)b << 15) + base;
    #pragma unroll
    for (int s = 0; s < 8; ++s) { int i = t + s*512; smem[i] = seg[i]; }
    __syncthreads();
    for (int j = 2048; j > 0; j >>= 1) {
        #pragma unroll
        for (int pp = 0; pp < 4; ++pp) {
            int p = t + pp * 512;
            int i = ((p & ~(j-1)) << 1) | (p & (j-1));
            int l = i | j;
            bool up = (((base + i) & k) == 0);
            unsigned long long a = smem[i], c = smem[l];
            if ((a > c) == up) { smem[i] = c; smem[l] = a; }
        }
        __syncthreads();
    }
    #pragma unroll
    for (int s = 0; s < 8; ++s) { int i = t + s*512; seg[i] = smem[i]; }
}

// one global strided compare-exchange step (j >= 4096)
__global__ __launch_bounds__(256) void sort_global_kernel(
    unsigned long long* __restrict__ comps, int j, int k)
{
    int gid = blockIdx.x * blockDim.x + threadIdx.x;   // NB * N_PAD/2 threads
    int b = gid >> 14, p = gid & 16383;
    unsigned long long* seg = comps + ((size_t)b << 15);
    int i = ((p & ~(j-1)) << 1) | (p & (j-1));
    int l = i | j;
    bool up = ((i & k) == 0);
    unsigned long long a = seg[i], c = seg[l];
    if ((a > c) == up) { seg[i] = c; seg[l] = a; }
}

// gather sorted token rows + write idx / mask / scalars
__global__ __launch_bounds__(256) void gather_kernel(
    const unsigned long long* __restrict__ comps,
    const float* __restrict__ lidar_tokens,
    const float* __restrict__ img_tokens,
    const unsigned char* __restrict__ lmask,
    const unsigned char* __restrict__ imask,
    float* __restrict__ out)
{
    int row  = blockIdx.x * 4 + (threadIdx.x >> 6);   // 4 rows per block
    int lane = threadIdx.x & 63;
    int b = row / N_TOT, pos = row - b * N_TOT;
    unsigned long long comp = comps[((size_t)b << 15) + pos];
    int src = (int)(comp & 0xFFFFu);
    const float4* srcp;
    if (src < N_LIDAR)
        srcp = (const float4*)(lidar_tokens + ((size_t)b * N_LIDAR + src) * NC);
    else
        srcp = (const float4*)(img_tokens + ((size_t)b * N_IMG + (src - N_LIDAR)) * NC);
    float4* dstp = (float4*)(out + (size_t)row * NC);
    dstp[lane] = srcp[lane];
    if (lane == 0) {
        out[TOK_END + row] = (float)src;
        bool m = (src < N_LIDAR) ? (lmask[b * N_LIDAR + src] != 0)
                                 : (imask[b * N_IMG + (src - N_LIDAR)] != 0);
        out[IDX_END + row] = m ? 1.0f : 0.0f;
        if (row == 0) {
            out[MSK_END]     = (float)N_LIDAR;
            out[MSK_END + 1] = 1.0f;
        }
    }
}

extern "C" void kernel_launch(void* const* d_in, const int* in_sizes, int n_in,
                              void* d_out, int out_size, void* d_ws, size_t ws_size,
                              hipStream_t stream) {
    const float* lidar_tokens = (const float*)d_in[0];
    const float* lidar_coords = (const float*)d_in[1];
    const float* img_tokens   = (const float*)d_in[2];
    const float* img_kuvd     = (const float*)d_in[3];
    const float* Kmat         = (const float*)d_in[4];
    const float* Tmat         = (const float*)d_in[5];
    const float* postR        = (const float*)d_in[6];
    const float* postT        = (const float*)d_in[7];
    const unsigned char* lmask = (const unsigned char*)d_in[8];
    const unsigned char* imask = (const unsigned char*)d_in[9];
    float* out = (float*)d_out;

    char* ws = (char*)d_ws;
    unsigned long long* comps = (unsigned long long*)(ws + WS_COMPS_OFF);
    int4* qbuf = (int4*)(ws + WS_QBUF_OFF);
    int*  mm   = (int*)(ws + WS_MM_OFF);

    init_mm_kernel<<<1, 64, 0, stream>>>(mm);
    quant_kernel<<<(NB * N_TOT) / 256, 256, 0, stream>>>(
        lidar_coords, img_kuvd, Kmat, Tmat, postR, postT, qbuf, mm);

    // local sort of 4096-segments (keys built in-kernel)
    sort_local_full_kernel<<<32, 512, 0, stream>>>(qbuf, mm, lmask, imask, comps);

    const int GBLK = (NB * N_PAD / 2) / 256;   // 256 blocks
    // k = 8192
    sort_global_kernel<<<GBLK, 256, 0, stream>>>(comps, 4096, 8192);
    sort_local_merge_kernel<<<32, 512, 0, stream>>>(comps, 8192);
    // k = 16384
    sort_global_kernel<<<GBLK, 256, 0, stream>>>(comps, 8192, 16384);
    sort_global_kernel<<<GBLK, 256, 0, stream>>>(comps, 4096, 16384);
    sort_local_merge_kernel<<<32, 512, 0, stream>>>(comps, 16384);
    // k = 32768
    sort_global_kernel<<<GBLK, 256, 0, stream>>>(comps, 16384, 32768);
    sort_global_kernel<<<GBLK, 256, 0, stream>>>(comps, 8192, 32768);
    sort_global_kernel<<<GBLK, 256, 0, stream>>>(comps, 4096, 32768);
    sort_local_merge_kernel<<<32, 512, 0, stream>>>(comps, 32768);

    gather_kernel<<<(NB * N_TOT) / 4, 256, 0, stream>>>(
        comps, lidar_tokens, img_tokens, lmask, imask, out);
}

// Round 4
// 244.152 us; speedup vs baseline: 1.2811x; 1.2811x over previous
//
#include <hip/hip_runtime.h>
#include <stdint.h>

// ---- problem dims (fixed by reference setup_inputs) ----
#define NB      4
#define N_LIDAR 16384
#define N_IMG   4096
#define N_TOT   20480          // N_LIDAR + N_IMG
#define N_PAD   32768          // next pow2 for bitonic sort
#define NC      256
#define NVIEWS  6
#define MULTK   100000LL
#define BLOCKS_PER_B 80        // quant blocks per batch (20480/256)

// d_out layout (all float32):
//   [0, TOK_END)                 sorted_tokens  [B,N,C]
//   [TOK_END, IDX_END)           idx (as float)
//   [IDX_END, MSK_END)           sorted_mask (0/1 float)
//   [MSK_END], [MSK_END+1]       16384.0f, 1.0f
#define TOK_END ((size_t)NB * N_TOT * NC)
#define IDX_END (TOK_END + (size_t)NB * N_TOT)
#define MSK_END (IDX_END + (size_t)NB * N_TOT)

// ---- workspace layout ----
#define WS_COMPS_OFF 0                                        // NB*N_PAD u64 (1 MiB)
#define WS_QBUF_OFF  ((size_t)NB * N_PAD * 8)                 // NB*N_TOT int4
#define WS_MM_OFF    (WS_QBUF_OFF + (size_t)NB * N_TOT * 16)  // 24 ints
#define WS_BMM_OFF   (WS_MM_OFF + 256)                        // NB*80*6 ints

// one thread per point: quantize; wave-reduce + block-reduce min/max;
// NO global atomics (they serialized quant at 62us in R2) — per-block results out.
__global__ __launch_bounds__(256) void quant_kernel(
    const float* __restrict__ lidar_coords,
    const float* __restrict__ kuvd,
    const float* __restrict__ Kmat,
    const float* __restrict__ Tmat,
    const float* __restrict__ postR,
    const float* __restrict__ postT,
    int4* __restrict__ qbuf, int* __restrict__ blockmm)
{
    int gid = blockIdx.x * blockDim.x + threadIdx.x;   // exactly NB*N_TOT threads
    int b = gid / N_TOT, i = gid - b * N_TOT;          // blocks never straddle batches
    int q0, q1, q2;
    if (i < N_LIDAR) {
        const float* c = lidar_coords + ((size_t)b * N_LIDAR + i) * 3;
        q0 = (int)floorf(c[0]);
        q1 = (int)floorf(c[1]);
        q2 = (int)floorf(c[2]);
    } else {
        int ii = i - N_LIDAR;
        const float* kv = kuvd + ((size_t)b * N_IMG + ii) * 4;
        int cam = (int)kv[0];
        double u = kv[1], v = kv[2], D = kv[3];
        const float* R  = postR + ((size_t)b * NVIEWS + cam) * 9;
        const float* t  = postT + ((size_t)b * NVIEWS + cam) * 3;
        const float* Km = Kmat  + ((size_t)b * NVIEWS + cam) * 9;
        const float* T  = Tmat  + ((size_t)b * NVIEWS + cam) * 16;
        double x0 = u - (double)t[0];
        double x1 = v - (double)t[1];
        double x2 = 1.0 - (double)t[2];
        // inverse of post_rot (3x3) via adjugate, f64
        double r00=R[0], r01=R[1], r02=R[2];
        double r10=R[3], r11=R[4], r12=R[5];
        double r20=R[6], r21=R[7], r22=R[8];
        double c00 = r11*r22 - r12*r21;
        double c01 = r02*r21 - r01*r22;
        double c02 = r01*r12 - r02*r11;
        double c10 = r12*r20 - r10*r22;
        double c11 = r00*r22 - r02*r20;
        double c12 = r02*r10 - r00*r12;
        double det = r00*(r11*r22 - r12*r21)
                   - r01*(r10*r22 - r12*r20)
                   + r02*(r10*r21 - r11*r20);
        double inv = 1.0 / det;
        double w0 = (c00*x0 + c01*x1 + c02*x2) * inv;
        double w1 = (c10*x0 + c11*x1 + c12*x2) * inv;
        double fx = Km[0], cx = Km[2], fy = Km[4], cy = Km[5];
        double camx = (w0 - cx) / fx * D;
        double camy = (w1 - cy) / fy * D;
        double camz = D;
        double wx = (double)T[0]*camx + (double)T[1]*camy + (double)T[2]*camz  + (double)T[3];
        double wy = (double)T[4]*camx + (double)T[5]*camy + (double)T[6]*camz  + (double)T[7];
        double wz = (double)T[8]*camx + (double)T[9]*camy + (double)T[10]*camz + (double)T[11];
        q0 = (int)floor(wx);
        q1 = (int)floor(wy);
        q2 = (int)floor(wz);
    }
    qbuf[gid] = make_int4(q0, q1, q2, 0);

    // wave-level min/max reduction
    int mn0=q0, mx0=q0, mn1=q1, mx1=q1, mn2=q2, mx2=q2;
    #pragma unroll
    for (int off = 32; off; off >>= 1) {
        mn0 = min(mn0, __shfl_xor(mn0, off));
        mx0 = max(mx0, __shfl_xor(mx0, off));
        mn1 = min(mn1, __shfl_xor(mn1, off));
        mx1 = max(mx1, __shfl_xor(mx1, off));
        mn2 = min(mn2, __shfl_xor(mn2, off));
        mx2 = max(mx2, __shfl_xor(mx2, off));
    }
    __shared__ int sred[4][6];
    int wid = threadIdx.x >> 6;
    if ((threadIdx.x & 63) == 0) {
        sred[wid][0]=mn0; sred[wid][1]=mn1; sred[wid][2]=mn2;
        sred[wid][3]=mx0; sred[wid][4]=mx1; sred[wid][5]=mx2;
    }
    __syncthreads();
    if (threadIdx.x == 0) {
        int v0=sred[0][0], v1=sred[0][1], v2=sred[0][2];
        int v3=sred[0][3], v4=sred[0][4], v5=sred[0][5];
        #pragma unroll
        for (int w = 1; w < 4; ++w) {
            v0=min(v0,sred[w][0]); v1=min(v1,sred[w][1]); v2=min(v2,sred[w][2]);
            v3=max(v3,sred[w][3]); v4=max(v4,sred[w][4]); v5=max(v5,sred[w][5]);
        }
        int* dst = blockmm + blockIdx.x * 6;
        dst[0]=v0; dst[1]=v1; dst[2]=v2; dst[3]=v3; dst[4]=v4; dst[5]=v5;
    }
}

// reduce 80 per-block results per batch -> mm (12 mins then 12 maxes)
__global__ __launch_bounds__(128) void reduce_mm_kernel(
    const int* __restrict__ blockmm, int* __restrict__ mm)
{
    int b = blockIdx.x;                     // 4 blocks
    int t = threadIdx.x;                    // 128 threads (2 waves)
    __shared__ int swave[2][6];
    int v[6];
    if (t < BLOCKS_PER_B) {
        const int* src = blockmm + (b * BLOCKS_PER_B + t) * 6;
        #pragma unroll
        for (int c = 0; c < 6; ++c) v[c] = src[c];
    } else {
        v[0]=v[1]=v[2]=0x7FFFFFFF;
        v[3]=v[4]=v[5]=(int)0x80000000;
    }
    #pragma unroll
    for (int off = 32; off; off >>= 1) {
        v[0]=min(v[0],__shfl_xor(v[0],off));
        v[1]=min(v[1],__shfl_xor(v[1],off));
        v[2]=min(v[2],__shfl_xor(v[2],off));
        v[3]=max(v[3],__shfl_xor(v[3],off));
        v[4]=max(v[4],__shfl_xor(v[4],off));
        v[5]=max(v[5],__shfl_xor(v[5],off));
    }
    int wid = t >> 6;
    if ((t & 63) == 0) {
        #pragma unroll
        for (int c = 0; c < 6; ++c) swave[wid][c] = v[c];
    }
    __syncthreads();
    if (t == 0) {
        mm[b*3+0]      = min(swave[0][0], swave[1][0]);
        mm[b*3+1]      = min(swave[0][1], swave[1][1]);
        mm[b*3+2]      = min(swave[0][2], swave[1][2]);
        mm[12 + b*3+0] = max(swave[0][3], swave[1][3]);
        mm[12 + b*3+1] = max(swave[0][4], swave[1][4]);
        mm[12 + b*3+2] = max(swave[0][5], swave[1][5]);
    }
}

// sortable composite: (key << 16) | original_index ; padding = all-ones.
// Ascending sort of composites == stable argsort of keys (real keys < 2^42).
__device__ inline unsigned long long make_comp(
    int b, int i, const int4* __restrict__ qbuf, const int* __restrict__ mm,
    const unsigned char* __restrict__ lmask, const unsigned char* __restrict__ imask)
{
    if (i >= N_TOT) return ~0ull;
    int4 q = qbuf[b * N_TOT + i];
    int mn0 = mm[b*3+0], mn1 = mm[b*3+1], mn2 = mm[b*3+2];
    int d0 = q.x - mn0, d1 = q.y - mn1, d2 = q.z - mn2;
    int max1 = mm[12 + b*3+1] - mn1;
    int max2 = mm[12 + b*3+2] - mn2;
    long long s1 = (d0 & 1) ? (long long)(max1 - d1) : (long long)d1;
    long long s2 = ((d0 + d1) & 1) ? (long long)(max2 - d2) : (long long)d2;
    long long key = (long long)d0 * (MULTK * MULTK) + s1 * MULTK + s2;
    bool m = (i < N_LIDAR) ? (lmask[b * N_LIDAR + i] != 0)
                           : (imask[b * N_IMG + (i - N_LIDAR)] != 0);
    if (m) key = (1LL << 45);   // after every real key; stable among masked
    return ((unsigned long long)key << 16) | (unsigned)i;
}

// full local bitonic sort of a 4096-element segment (key build fused in)
__global__ __launch_bounds__(1024) void sort_local_full_kernel(
    const int4* __restrict__ qbuf, const int* __restrict__ mm,
    const unsigned char* __restrict__ lmask, const unsigned char* __restrict__ imask,
    unsigned long long* __restrict__ comps)
{
    __shared__ unsigned long long smem[4096];   // 32 KiB
    int blk = blockIdx.x;                       // 32 blocks
    int b = blk >> 3, bb = blk & 7;
    int base = bb * 4096;
    int t = threadIdx.x;
    #pragma unroll
    for (int s = 0; s < 4; ++s) {
        int i = t + s * 1024;
        smem[i] = make_comp(b, base + i, qbuf, mm, lmask, imask);
    }
    __syncthreads();
    for (int k = 2; k <= 4096; k <<= 1) {
        for (int j = k >> 1; j > 0; j >>= 1) {
            #pragma unroll
            for (int pp = 0; pp < 2; ++pp) {
                int p = t + pp * 1024;                      // pair idx [0,2048)
                int i = ((p & ~(j-1)) << 1) | (p & (j-1));
                int l = i | j;
                bool up = (((base + i) & k) == 0);
                unsigned long long a = smem[i], c = smem[l];
                if ((a > c) == up) { smem[i] = c; smem[l] = a; }
            }
            __syncthreads();
        }
    }
    unsigned long long* seg = comps + ((size_t)b << 15) + base;
    #pragma unroll
    for (int s = 0; s < 4; ++s) { int i = t + s*1024; seg[i] = smem[i]; }
}

// local merge: j = 2048 .. 1 for phase k
__global__ __launch_bounds__(1024) void sort_local_merge_kernel(
    unsigned long long* __restrict__ comps, int k)
{
    __shared__ unsigned long long smem[4096];
    int blk = blockIdx.x;
    int b = blk >> 3, bb = blk & 7;
    int base = bb * 4096;
    int t = threadIdx.x;
    unsigned long long* seg = comps + ((size_t)b << 15) + base;
    #pragma unroll
    for (int s = 0; s < 4; ++s) { int i = t + s*1024; smem[i] = seg[i]; }
    __syncthreads();
    for (int j = 2048; j > 0; j >>= 1) {
        #pragma unroll
        for (int pp = 0; pp < 2; ++pp) {
            int p = t + pp * 1024;
            int i = ((p & ~(j-1)) << 1) | (p & (j-1));
            int l = i | j;
            bool up = (((base + i) & k) == 0);
            unsigned long long a = smem[i], c = smem[l];
            if ((a > c) == up) { smem[i] = c; smem[l] = a; }
        }
        __syncthreads();
    }
    #pragma unroll
    for (int s = 0; s < 4; ++s) { int i = t + s*1024; seg[i] = smem[i]; }
}

// All global steps of phase K (j = 16384/8192/4096 as applicable) in registers:
// they only touch index bits 12-14, so a thread owning {low + m*4096, m=0..7}
// does the whole global part locally. Fully static indexing (no scratch).
template<int JM, int K>
__device__ inline void phase_step(unsigned long long (&e)[8], int low) {
    #pragma unroll
    for (int m = 0; m < 8; ++m) {
        if ((m & JM) == 0) {
            int p = m | JM;
            int i_idx = low + (m << 12);            // smaller global index of pair
            bool up = ((i_idx & K) == 0);
            unsigned long long a = e[m], c = e[p];
            if ((a > c) == up) { e[m] = c; e[p] = a; }
        }
    }
}

template<int K>
__global__ __launch_bounds__(256) void sort_phase_global_kernel(
    unsigned long long* __restrict__ comps)
{
    int gid = blockIdx.x * blockDim.x + threadIdx.x;   // NB*4096 threads
    int b = gid >> 12, low = gid & 4095;
    unsigned long long* seg = comps + ((size_t)b << 15);
    unsigned long long e[8];
    #pragma unroll
    for (int m = 0; m < 8; ++m) e[m] = seg[low + (m << 12)];
    if constexpr (K >= 32768) phase_step<4, K>(e, low);
    if constexpr (K >= 16384) phase_step<2, K>(e, low);
    phase_step<1, K>(e, low);
    #pragma unroll
    for (int m = 0; m < 8; ++m) seg[low + (m << 12)] = e[m];
}

// gather sorted token rows + write idx / mask / scalars
__global__ __launch_bounds__(256) void gather_kernel(
    const unsigned long long* __restrict__ comps,
    const float* __restrict__ lidar_tokens,
    const float* __restrict__ img_tokens,
    const unsigned char* __restrict__ lmask,
    const unsigned char* __restrict__ imask,
    float* __restrict__ out)
{
    int row  = blockIdx.x * 4 + (threadIdx.x >> 6);   // 4 rows per block
    int lane = threadIdx.x & 63;
    int b = row / N_TOT, pos = row - b * N_TOT;
    unsigned long long comp = comps[((size_t)b << 15) + pos];
    int src = (int)(comp & 0xFFFFu);
    const float4* srcp;
    if (src < N_LIDAR)
        srcp = (const float4*)(lidar_tokens + ((size_t)b * N_LIDAR + src) * NC);
    else
        srcp = (const float4*)(img_tokens + ((size_t)b * N_IMG + (src - N_LIDAR)) * NC);
    float4* dstp = (float4*)(out + (size_t)row * NC);
    dstp[lane] = srcp[lane];
    if (lane == 0) {
        out[TOK_END + row] = (float)src;
        bool m = (src < N_LIDAR) ? (lmask[b * N_LIDAR + src] != 0)
                                 : (imask[b * N_IMG + (src - N_LIDAR)] != 0);
        out[IDX_END + row] = m ? 1.0f : 0.0f;
        if (row == 0) {
            out[MSK_END]     = (float)N_LIDAR;
            out[MSK_END + 1] = 1.0f;
        }
    }
}

extern "C" void kernel_launch(void* const* d_in, const int* in_sizes, int n_in,
                              void* d_out, int out_size, void* d_ws, size_t ws_size,
                              hipStream_t stream) {
    const float* lidar_tokens = (const float*)d_in[0];
    const float* lidar_coords = (const float*)d_in[1];
    const float* img_tokens   = (const float*)d_in[2];
    const float* img_kuvd     = (const float*)d_in[3];
    const float* Kmat         = (const float*)d_in[4];
    const float* Tmat         = (const float*)d_in[5];
    const float* postR        = (const float*)d_in[6];
    const float* postT        = (const float*)d_in[7];
    const unsigned char* lmask = (const unsigned char*)d_in[8];
    const unsigned char* imask = (const unsigned char*)d_in[9];
    float* out = (float*)d_out;

    char* ws = (char*)d_ws;
    unsigned long long* comps = (unsigned long long*)(ws + WS_COMPS_OFF);
    int4* qbuf    = (int4*)(ws + WS_QBUF_OFF);
    int*  mm      = (int*)(ws + WS_MM_OFF);
    int*  blockmm = (int*)(ws + WS_BMM_OFF);

    quant_kernel<<<(NB * N_TOT) / 256, 256, 0, stream>>>(
        lidar_coords, img_kuvd, Kmat, Tmat, postR, postT, qbuf, blockmm);
    reduce_mm_kernel<<<NB, 128, 0, stream>>>(blockmm, mm);

    // local sort of 4096-segments (keys built in-kernel)
    sort_local_full_kernel<<<32, 1024, 0, stream>>>(qbuf, mm, lmask, imask, comps);

    const int PBLK = (NB * 4096) / 256;   // 64 blocks
    // k = 8192
    sort_phase_global_kernel<8192><<<PBLK, 256, 0, stream>>>(comps);
    sort_local_merge_kernel<<<32, 1024, 0, stream>>>(comps, 8192);
    // k = 16384
    sort_phase_global_kernel<16384><<<PBLK, 256, 0, stream>>>(comps);
    sort_local_merge_kernel<<<32, 1024, 0, stream>>>(comps, 16384);
    // k = 32768
    sort_phase_global_kernel<32768><<<PBLK, 256, 0, stream>>>(comps);
    sort_local_merge_kernel<<<32, 1024, 0, stream>>>(comps, 32768);

    gather_kernel<<<(NB * N_TOT) / 4, 256, 0, stream>>>(
        comps, lidar_tokens, img_tokens, lmask, imask, out);
}

// Round 6
// 241.560 us; speedup vs baseline: 1.2948x; 1.0107x over previous
//
#include <hip/hip_runtime.h>
#include <stdint.h>

// ---- problem dims (fixed by reference setup_inputs) ----
#define NB      4
#define N_LIDAR 16384
#define N_IMG   4096
#define N_TOT   20480          // N_LIDAR + N_IMG
#define N_PAD   32768          // next pow2 for bitonic sort
#define NC      256
#define NVIEWS  6
#define MULTK   100000LL
#define BLOCKS_PER_B 80        // quant blocks per batch (20480/256)

// d_out layout (all float32):
//   [0, TOK_END)                 sorted_tokens  [B,N,C]
//   [TOK_END, IDX_END)           idx (as float)
//   [IDX_END, MSK_END)           sorted_mask (0/1 float)
//   [MSK_END], [MSK_END+1]       16384.0f, 1.0f
#define TOK_END ((size_t)NB * N_TOT * NC)
#define IDX_END (TOK_END + (size_t)NB * N_TOT)
#define MSK_END (IDX_END + (size_t)NB * N_TOT)

// ---- workspace layout ----
// compsA : NB*N_PAD u64 (1 MiB)
// qbuf   : NB*N_TOT int4 (1.25 MiB) -- DOUBLES as compsB once sort starts
//          (qbuf is dead after sort_local_full; ping-pong avoids the
//           cross-block read/write race in the fused phase kernels)
// blockmm: NB*80*6 ints
#define WS_COMPSA_OFF 0
#define WS_QBUF_OFF   ((size_t)NB * N_PAD * 8)
#define WS_COMPSB_OFF WS_QBUF_OFF
#define WS_BMM_OFF    (WS_QBUF_OFF + (size_t)NB * N_TOT * 16)

// one thread per point: quantize; wave+block min/max reduce; per-block out
// (global atomics removed in R3 -- they serialized quant at 62us in R2)
__global__ __launch_bounds__(256) void quant_kernel(
    const float* __restrict__ lidar_coords,
    const float* __restrict__ kuvd,
    const float* __restrict__ Kmat,
    const float* __restrict__ Tmat,
    const float* __restrict__ postR,
    const float* __restrict__ postT,
    int4* __restrict__ qbuf, int* __restrict__ blockmm)
{
    int gid = blockIdx.x * blockDim.x + threadIdx.x;   // exactly NB*N_TOT threads
    int b = gid / N_TOT, i = gid - b * N_TOT;          // blocks never straddle batches
    int q0, q1, q2;
    if (i < N_LIDAR) {
        const float* c = lidar_coords + ((size_t)b * N_LIDAR + i) * 3;
        q0 = (int)floorf(c[0]);
        q1 = (int)floorf(c[1]);
        q2 = (int)floorf(c[2]);
    } else {
        int ii = i - N_LIDAR;
        const float* kv = kuvd + ((size_t)b * N_IMG + ii) * 4;
        int cam = (int)kv[0];
        double u = kv[1], v = kv[2], D = kv[3];
        const float* R  = postR + ((size_t)b * NVIEWS + cam) * 9;
        const float* t  = postT + ((size_t)b * NVIEWS + cam) * 3;
        const float* Km = Kmat  + ((size_t)b * NVIEWS + cam) * 9;
        const float* T  = Tmat  + ((size_t)b * NVIEWS + cam) * 16;
        double x0 = u - (double)t[0];
        double x1 = v - (double)t[1];
        double x2 = 1.0 - (double)t[2];
        double r00=R[0], r01=R[1], r02=R[2];
        double r10=R[3], r11=R[4], r12=R[5];
        double r20=R[6], r21=R[7], r22=R[8];
        double c00 = r11*r22 - r12*r21;
        double c01 = r02*r21 - r01*r22;
        double c02 = r01*r12 - r02*r11;
        double c10 = r12*r20 - r10*r22;
        double c11 = r00*r22 - r02*r20;
        double c12 = r02*r10 - r00*r12;
        double det = r00*(r11*r22 - r12*r21)
                   - r01*(r10*r22 - r12*r20)
                   + r02*(r10*r21 - r11*r20);
        double inv = 1.0 / det;
        double w0 = (c00*x0 + c01*x1 + c02*x2) * inv;
        double w1 = (c10*x0 + c11*x1 + c12*x2) * inv;
        double fx = Km[0], cx = Km[2], fy = Km[4], cy = Km[5];
        double camx = (w0 - cx) / fx * D;
        double camy = (w1 - cy) / fy * D;
        double camz = D;
        double wx = (double)T[0]*camx + (double)T[1]*camy + (double)T[2]*camz  + (double)T[3];
        double wy = (double)T[4]*camx + (double)T[5]*camy + (double)T[6]*camz  + (double)T[7];
        double wz = (double)T[8]*camx + (double)T[9]*camy + (double)T[10]*camz + (double)T[11];
        q0 = (int)floor(wx);
        q1 = (int)floor(wy);
        q2 = (int)floor(wz);
    }
    qbuf[gid] = make_int4(q0, q1, q2, 0);

    int mn0=q0, mx0=q0, mn1=q1, mx1=q1, mn2=q2, mx2=q2;
    #pragma unroll
    for (int off = 32; off; off >>= 1) {
        mn0 = min(mn0, __shfl_xor(mn0, off));
        mx0 = max(mx0, __shfl_xor(mx0, off));
        mn1 = min(mn1, __shfl_xor(mn1, off));
        mx1 = max(mx1, __shfl_xor(mx1, off));
        mn2 = min(mn2, __shfl_xor(mn2, off));
        mx2 = max(mx2, __shfl_xor(mx2, off));
    }
    __shared__ int sred[4][6];
    int wid = threadIdx.x >> 6;
    if ((threadIdx.x & 63) == 0) {
        sred[wid][0]=mn0; sred[wid][1]=mn1; sred[wid][2]=mn2;
        sred[wid][3]=mx0; sred[wid][4]=mx1; sred[wid][5]=mx2;
    }
    __syncthreads();
    if (threadIdx.x == 0) {
        int v0=sred[0][0], v1=sred[0][1], v2=sred[0][2];
        int v3=sred[0][3], v4=sred[0][4], v5=sred[0][5];
        #pragma unroll
        for (int w = 1; w < 4; ++w) {
            v0=min(v0,sred[w][0]); v1=min(v1,sred[w][1]); v2=min(v2,sred[w][2]);
            v3=max(v3,sred[w][3]); v4=max(v4,sred[w][4]); v5=max(v5,sred[w][5]);
        }
        int* dst = blockmm + blockIdx.x * 6;
        dst[0]=v0; dst[1]=v1; dst[2]=v2; dst[3]=v3; dst[4]=v4; dst[5]=v5;
    }
}

// sortable composite: (key << 16) | original_index ; padding = all-ones.
// Ascending sort of composites == stable argsort of keys (real keys < 2^42).
__device__ inline unsigned long long make_comp2(
    int b, int i, const int4* __restrict__ qbuf,
    int mn0, int mn1, int mn2, int max1, int max2,
    const unsigned char* __restrict__ lmask, const unsigned char* __restrict__ imask)
{
    if (i >= N_TOT) return ~0ull;
    int4 q = qbuf[b * N_TOT + i];
    int d0 = q.x - mn0, d1 = q.y - mn1, d2 = q.z - mn2;
    long long s1 = (d0 & 1) ? (long long)(max1 - d1) : (long long)d1;
    long long s2 = ((d0 + d1) & 1) ? (long long)(max2 - d2) : (long long)d2;
    long long key = (long long)d0 * (MULTK * MULTK) + s1 * MULTK + s2;
    bool m = (i < N_LIDAR) ? (lmask[b * N_LIDAR + i] != 0)
                           : (imask[b * N_IMG + (i - N_LIDAR)] != 0);
    if (m) key = (1LL << 45);   // after every real key; stable among masked
    return ((unsigned long long)key << 16) | (unsigned)i;
}

// full local bitonic sort of a 4096-element segment.
// mm reduction folded in: wave 0 reduces this batch's 80 blockmm rows
// (redundantly per block, ~2KB read) -- removes the reduce_mm dispatch.
__global__ __launch_bounds__(1024) void sort_local_full_kernel(
    const int4* __restrict__ qbuf, const int* __restrict__ blockmm,
    const unsigned char* __restrict__ lmask, const unsigned char* __restrict__ imask,
    unsigned long long* __restrict__ comps)
{
    __shared__ unsigned long long smem[4096];   // 32 KiB
    __shared__ int smm[6];
    int blk = blockIdx.x;                       // 32 blocks
    int b = blk >> 3, bb = blk & 7;
    int base = bb * 4096;
    int t = threadIdx.x;

    if (t < 64) {                                // wave 0: reduce batch b's mins/maxes
        const int* src = blockmm + (b * BLOCKS_PER_B + t) * 6;
        int v0 = src[0], v1 = src[1], v2 = src[2];
        int v3 = src[3], v4 = src[4], v5 = src[5];
        if (t < BLOCKS_PER_B - 64) {
            const int* s2 = blockmm + (b * BLOCKS_PER_B + 64 + t) * 6;
            v0 = min(v0, s2[0]); v1 = min(v1, s2[1]); v2 = min(v2, s2[2]);
            v3 = max(v3, s2[3]); v4 = max(v4, s2[4]); v5 = max(v5, s2[5]);
        }
        #pragma unroll
        for (int off = 32; off; off >>= 1) {
            v0 = min(v0, __shfl_xor(v0, off));
            v1 = min(v1, __shfl_xor(v1, off));
            v2 = min(v2, __shfl_xor(v2, off));
            v3 = max(v3, __shfl_xor(v3, off));
            v4 = max(v4, __shfl_xor(v4, off));
            v5 = max(v5, __shfl_xor(v5, off));
        }
        if (t == 0) { smm[0]=v0; smm[1]=v1; smm[2]=v2; smm[3]=v3; smm[4]=v4; smm[5]=v5; }
    }
    __syncthreads();
    int mn0 = smm[0], mn1 = smm[1], mn2 = smm[2];
    int max1 = smm[4] - mn1, max2 = smm[5] - mn2;

    #pragma unroll
    for (int s = 0; s < 4; ++s) {
        int i = t + s * 1024;
        smem[i] = make_comp2(b, base + i, qbuf, mn0, mn1, mn2, max1, max2, lmask, imask);
    }
    __syncthreads();
    for (int k = 2; k <= 4096; k <<= 1) {
        for (int j = k >> 1; j > 0; j >>= 1) {
            #pragma unroll
            for (int pp = 0; pp < 2; ++pp) {
                int p = t + pp * 1024;                      // pair idx [0,2048)
                int i = ((p & ~(j-1)) << 1) | (p & (j-1));
                int l = i | j;
                bool up = (((base + i) & k) == 0);
                unsigned long long a = smem[i], c = smem[l];
                if ((a > c) == up) { smem[i] = c; smem[l] = a; }
            }
            __syncthreads();
        }
    }
    unsigned long long* seg = comps + ((size_t)b << 15) + base;
    #pragma unroll
    for (int s = 0; s < 4; ++s) { int i = t + s*1024; seg[i] = smem[i]; }
}

// Fused phase-K kernel (K = C*4096): block bb loads its column GROUP
// (C columns, stride-4096), replays the register phase steps locally and
// keeps its own column (redundant loads, L2-trivial), then LDS-merges
// j=2048..1. Direction is uniform per block: (bb & C)==0 for both phase
// and merge since index bits < 12 can't affect (idx & K) for K>=8192.
// in != out (ping-pong) because other blocks concurrently write their columns.
template<int C>
__global__ __launch_bounds__(1024) void sort_phase_fused_kernel(
    const unsigned long long* __restrict__ in, unsigned long long* __restrict__ outc)
{
    __shared__ unsigned long long smem[4096];
    int blk = blockIdx.x;                       // 32 blocks
    int b = blk >> 3, bb = blk & 7;
    const int g0 = bb & ~(C - 1);
    const int sel = bb & (C - 1);
    const bool up = ((bb & C) == 0);
    const unsigned long long* inseg = in + ((size_t)b << 15);
    int t = threadIdx.x;
    #pragma unroll
    for (int s = 0; s < 4; ++s) {
        int low = t + s * 1024;
        unsigned long long e[C];
        #pragma unroll
        for (int mi = 0; mi < C; ++mi)
            e[mi] = inseg[low + ((g0 + mi) << 12)];
        #pragma unroll
        for (int JM = C >> 1; JM > 0; JM >>= 1) {
            #pragma unroll
            for (int mi = 0; mi < C; ++mi) {
                if ((mi & JM) == 0) {
                    unsigned long long a = e[mi], c2 = e[mi | JM];
                    if ((a > c2) == up) { e[mi] = c2; e[mi | JM] = a; }
                }
            }
        }
        unsigned long long keep = e[0];
        #pragma unroll
        for (int mi = 1; mi < C; ++mi) if (sel == mi) keep = e[mi];  // static idx only
        smem[low] = keep;
    }
    __syncthreads();
    for (int j = 2048; j > 0; j >>= 1) {
        #pragma unroll
        for (int pp = 0; pp < 2; ++pp) {
            int p = t + pp * 1024;
            int i = ((p & ~(j - 1)) << 1) | (p & (j - 1));
            int l = i | j;
            unsigned long long a = smem[i], c2 = smem[l];
            if ((a > c2) == up) { smem[i] = c2; smem[l] = a; }
        }
        __syncthreads();
    }
    unsigned long long* outseg = outc + ((size_t)b << 15) + bb * 4096;
    #pragma unroll
    for (int s = 0; s < 4; ++s) { int i = t + s * 1024; outseg[i] = smem[i]; }
}

// gather: 8 rows per wave for MLP (R4: 1 row/wave = dependent chain,
// 2.46 TB/s). One 64B comp load + shfl broadcast, then 8 independent
// 1KB row reads in flight, then 8 sequential row stores.
__global__ __launch_bounds__(256) void gather_kernel(
    const unsigned long long* __restrict__ comps,
    const float* __restrict__ lidar_tokens,
    const float* __restrict__ img_tokens,
    const unsigned char* __restrict__ lmask,
    const unsigned char* __restrict__ imask,
    float* __restrict__ out)
{
    int wave = threadIdx.x >> 6, lane = threadIdx.x & 63;
    int row0 = (blockIdx.x * 4 + wave) * 8;     // 8 consecutive rows, same batch (N_TOT%8==0)
    int b = row0 / N_TOT;
    int pos0 = row0 - b * N_TOT;
    unsigned long long carr = comps[((size_t)b << 15) + pos0 + (lane & 7)];
    int srcs[8];
    #pragma unroll
    for (int r = 0; r < 8; ++r)
        srcs[r] = (int)(__shfl(carr, r) & 0xFFFFu);
    float4 vals[8];
    #pragma unroll
    for (int r = 0; r < 8; ++r) {
        int s = srcs[r];
        const float4* p = (s < N_LIDAR)
            ? (const float4*)(lidar_tokens + ((size_t)b * N_LIDAR + s) * NC)
            : (const float4*)(img_tokens + ((size_t)b * N_IMG + (s - N_LIDAR)) * NC);
        vals[r] = p[lane];
    }
    #pragma unroll
    for (int r = 0; r < 8; ++r)
        ((float4*)(out + (size_t)(row0 + r) * NC))[lane] = vals[r];
    if (lane < 8) {
        int s = (int)(carr & 0xFFFFu);
        int row = row0 + lane;
        out[TOK_END + row] = (float)s;
        bool m = (s < N_LIDAR) ? (lmask[b * N_LIDAR + s] != 0)
                               : (imask[b * N_IMG + s - N_LIDAR] != 0);
        out[IDX_END + row] = m ? 1.0f : 0.0f;
    }
    if (row0 == 0 && lane == 0) {
        out[MSK_END]     = (float)N_LIDAR;
        out[MSK_END + 1] = 1.0f;
    }
}

extern "C" void kernel_launch(void* const* d_in, const int* in_sizes, int n_in,
                              void* d_out, int out_size, void* d_ws, size_t ws_size,
                              hipStream_t stream) {
    const float* lidar_tokens = (const float*)d_in[0];
    const float* lidar_coords = (const float*)d_in[1];
    const float* img_tokens   = (const float*)d_in[2];
    const float* img_kuvd     = (const float*)d_in[3];
    const float* Kmat         = (const float*)d_in[4];
    const float* Tmat         = (const float*)d_in[5];
    const float* postR        = (const float*)d_in[6];
    const float* postT        = (const float*)d_in[7];
    const unsigned char* lmask = (const unsigned char*)d_in[8];
    const unsigned char* imask = (const unsigned char*)d_in[9];
    float* out = (float*)d_out;

    char* ws = (char*)d_ws;
    unsigned long long* compsA = (unsigned long long*)(ws + WS_COMPSA_OFF);
    unsigned long long* compsB = (unsigned long long*)(ws + WS_COMPSB_OFF);
    int4* qbuf    = (int4*)(ws + WS_QBUF_OFF);      // aliases compsB (qbuf dead after local sort)
    int*  blockmm = (int*)(ws + WS_BMM_OFF);

    quant_kernel<<<(NB * N_TOT) / 256, 256, 0, stream>>>(
        lidar_coords, img_kuvd, Kmat, Tmat, postR, postT, qbuf, blockmm);

    sort_local_full_kernel<<<32, 1024, 0, stream>>>(qbuf, blockmm, lmask, imask, compsA);

    sort_phase_fused_kernel<2><<<32, 1024, 0, stream>>>(compsA, compsB);  // k=8192
    sort_phase_fused_kernel<4><<<32, 1024, 0, stream>>>(compsB, compsA);  // k=16384
    sort_phase_fused_kernel<8><<<32, 1024, 0, stream>>>(compsA, compsB);  // k=32768

    gather_kernel<<<(NB * N_TOT) / 32, 256, 0, stream>>>(
        compsB, lidar_tokens, img_tokens, lmask, imask, out);
}

// Round 8
// 237.647 us; speedup vs baseline: 1.3161x; 1.0165x over previous
//
#include <hip/hip_runtime.h>
#include <stdint.h>

// ---- problem dims (fixed by reference setup_inputs) ----
#define NB      4
#define N_LIDAR 16384
#define N_IMG   4096
#define N_TOT   20480          // N_LIDAR + N_IMG
#define N_PAD   32768          // next pow2 for bitonic sort
#define NC      256
#define NVIEWS  6
#define MULTK   100000LL
#define BLOCKS_PER_B 80        // quant blocks per batch (20480/256)

typedef float floatx4 __attribute__((ext_vector_type(4)));  // native vec for NT store

// d_out layout (all float32):
//   [0, TOK_END)                 sorted_tokens  [B,N,C]
//   [TOK_END, IDX_END)           idx (as float)
//   [IDX_END, MSK_END)           sorted_mask (0/1 float)
//   [MSK_END], [MSK_END+1]       16384.0f, 1.0f
#define TOK_END ((size_t)NB * N_TOT * NC)
#define IDX_END (TOK_END + (size_t)NB * N_TOT)
#define MSK_END (IDX_END + (size_t)NB * N_TOT)

// ---- workspace layout ----
// compsA : NB*N_PAD u64 (1 MiB)
// qbuf   : NB*N_TOT int4 (1.25 MiB) -- DOUBLES as compsB once sort starts
//          (qbuf is dead after sort_local_full; ping-pong avoids the
//           cross-block read/write race in the fused phase kernels)
// blockmm: NB*80*6 ints
#define WS_COMPSA_OFF 0
#define WS_QBUF_OFF   ((size_t)NB * N_PAD * 8)
#define WS_COMPSB_OFF WS_QBUF_OFF
#define WS_BMM_OFF    (WS_QBUF_OFF + (size_t)NB * N_TOT * 16)

// one thread per point: quantize; wave+block min/max reduce; per-block out
// (global atomics removed in R3 -- they serialized quant at 62us in R2)
__global__ __launch_bounds__(256) void quant_kernel(
    const float* __restrict__ lidar_coords,
    const float* __restrict__ kuvd,
    const float* __restrict__ Kmat,
    const float* __restrict__ Tmat,
    const float* __restrict__ postR,
    const float* __restrict__ postT,
    int4* __restrict__ qbuf, int* __restrict__ blockmm)
{
    int gid = blockIdx.x * blockDim.x + threadIdx.x;   // exactly NB*N_TOT threads
    int b = gid / N_TOT, i = gid - b * N_TOT;          // blocks never straddle batches
    int q0, q1, q2;
    if (i < N_LIDAR) {
        const float* c = lidar_coords + ((size_t)b * N_LIDAR + i) * 3;
        q0 = (int)floorf(c[0]);
        q1 = (int)floorf(c[1]);
        q2 = (int)floorf(c[2]);
    } else {
        int ii = i - N_LIDAR;
        const float* kv = kuvd + ((size_t)b * N_IMG + ii) * 4;
        int cam = (int)kv[0];
        double u = kv[1], v = kv[2], D = kv[3];
        const float* R  = postR + ((size_t)b * NVIEWS + cam) * 9;
        const float* t  = postT + ((size_t)b * NVIEWS + cam) * 3;
        const float* Km = Kmat  + ((size_t)b * NVIEWS + cam) * 9;
        const float* T  = Tmat  + ((size_t)b * NVIEWS + cam) * 16;
        double x0 = u - (double)t[0];
        double x1 = v - (double)t[1];
        double x2 = 1.0 - (double)t[2];
        double r00=R[0], r01=R[1], r02=R[2];
        double r10=R[3], r11=R[4], r12=R[5];
        double r20=R[6], r21=R[7], r22=R[8];
        double c00 = r11*r22 - r12*r21;
        double c01 = r02*r21 - r01*r22;
        double c02 = r01*r12 - r02*r11;
        double c10 = r12*r20 - r10*r22;
        double c11 = r00*r22 - r02*r20;
        double c12 = r02*r10 - r00*r12;
        double det = r00*(r11*r22 - r12*r21)
                   - r01*(r10*r22 - r12*r20)
                   + r02*(r10*r21 - r11*r20);
        double inv = 1.0 / det;
        double w0 = (c00*x0 + c01*x1 + c02*x2) * inv;
        double w1 = (c10*x0 + c11*x1 + c12*x2) * inv;
        double fx = Km[0], cx = Km[2], fy = Km[4], cy = Km[5];
        double camx = (w0 - cx) / fx * D;
        double camy = (w1 - cy) / fy * D;
        double camz = D;
        double wx = (double)T[0]*camx + (double)T[1]*camy + (double)T[2]*camz  + (double)T[3];
        double wy = (double)T[4]*camx + (double)T[5]*camy + (double)T[6]*camz  + (double)T[7];
        double wz = (double)T[8]*camx + (double)T[9]*camy + (double)T[10]*camz + (double)T[11];
        q0 = (int)floor(wx);
        q1 = (int)floor(wy);
        q2 = (int)floor(wz);
    }
    qbuf[gid] = make_int4(q0, q1, q2, 0);

    int mn0=q0, mx0=q0, mn1=q1, mx1=q1, mn2=q2, mx2=q2;
    #pragma unroll
    for (int off = 32; off; off >>= 1) {
        mn0 = min(mn0, __shfl_xor(mn0, off));
        mx0 = max(mx0, __shfl_xor(mx0, off));
        mn1 = min(mn1, __shfl_xor(mn1, off));
        mx1 = max(mx1, __shfl_xor(mx1, off));
        mn2 = min(mn2, __shfl_xor(mn2, off));
        mx2 = max(mx2, __shfl_xor(mx2, off));
    }
    __shared__ int sred[4][6];
    int wid = threadIdx.x >> 6;
    if ((threadIdx.x & 63) == 0) {
        sred[wid][0]=mn0; sred[wid][1]=mn1; sred[wid][2]=mn2;
        sred[wid][3]=mx0; sred[wid][4]=mx1; sred[wid][5]=mx2;
    }
    __syncthreads();
    if (threadIdx.x == 0) {
        int v0=sred[0][0], v1=sred[0][1], v2=sred[0][2];
        int v3=sred[0][3], v4=sred[0][4], v5=sred[0][5];
        #pragma unroll
        for (int w = 1; w < 4; ++w) {
            v0=min(v0,sred[w][0]); v1=min(v1,sred[w][1]); v2=min(v2,sred[w][2]);
            v3=max(v3,sred[w][3]); v4=max(v4,sred[w][4]); v5=max(v5,sred[w][5]);
        }
        int* dst = blockmm + blockIdx.x * 6;
        dst[0]=v0; dst[1]=v1; dst[2]=v2; dst[3]=v3; dst[4]=v4; dst[5]=v5;
    }
}

// sortable composite: (key << 16) | original_index ; padding = all-ones.
// Ascending sort of composites == stable argsort of keys (real keys < 2^42).
__device__ inline unsigned long long make_comp2(
    int b, int i, const int4* __restrict__ qbuf,
    int mn0, int mn1, int mn2, int max1, int max2,
    const unsigned char* __restrict__ lmask, const unsigned char* __restrict__ imask)
{
    if (i >= N_TOT) return ~0ull;
    int4 q = qbuf[b * N_TOT + i];
    int d0 = q.x - mn0, d1 = q.y - mn1, d2 = q.z - mn2;
    long long s1 = (d0 & 1) ? (long long)(max1 - d1) : (long long)d1;
    long long s2 = ((d0 + d1) & 1) ? (long long)(max2 - d2) : (long long)d2;
    long long key = (long long)d0 * (MULTK * MULTK) + s1 * MULTK + s2;
    bool m = (i < N_LIDAR) ? (lmask[b * N_LIDAR + i] != 0)
                           : (imask[b * N_IMG + (i - N_LIDAR)] != 0);
    if (m) key = (1LL << 45);   // after every real key; stable among masked
    return ((unsigned long long)key << 16) | (unsigned)i;
}

// full local bitonic sort of a 4096-element segment.
// mm reduction folded in: wave 0 reduces this batch's 80 blockmm rows
// (redundantly per block, ~2KB read) -- removes the reduce_mm dispatch.
__global__ __launch_bounds__(1024) void sort_local_full_kernel(
    const int4* __restrict__ qbuf, const int* __restrict__ blockmm,
    const unsigned char* __restrict__ lmask, const unsigned char* __restrict__ imask,
    unsigned long long* __restrict__ comps)
{
    __shared__ unsigned long long smem[4096];   // 32 KiB
    __shared__ int smm[6];
    int blk = blockIdx.x;                       // 32 blocks
    int b = blk >> 3, bb = blk & 7;
    int base = bb * 4096;
    int t = threadIdx.x;

    if (t < 64) {                                // wave 0: reduce batch b's mins/maxes
        const int* src = blockmm + (b * BLOCKS_PER_B + t) * 6;
        int v0 = src[0], v1 = src[1], v2 = src[2];
        int v3 = src[3], v4 = src[4], v5 = src[5];
        if (t < BLOCKS_PER_B - 64) {
            const int* s2 = blockmm + (b * BLOCKS_PER_B + 64 + t) * 6;
            v0 = min(v0, s2[0]); v1 = min(v1, s2[1]); v2 = min(v2, s2[2]);
            v3 = max(v3, s2[3]); v4 = max(v4, s2[4]); v5 = max(v5, s2[5]);
        }
        #pragma unroll
        for (int off = 32; off; off >>= 1) {
            v0 = min(v0, __shfl_xor(v0, off));
            v1 = min(v1, __shfl_xor(v1, off));
            v2 = min(v2, __shfl_xor(v2, off));
            v3 = max(v3, __shfl_xor(v3, off));
            v4 = max(v4, __shfl_xor(v4, off));
            v5 = max(v5, __shfl_xor(v5, off));
        }
        if (t == 0) { smm[0]=v0; smm[1]=v1; smm[2]=v2; smm[3]=v3; smm[4]=v4; smm[5]=v5; }
    }
    __syncthreads();
    int mn0 = smm[0], mn1 = smm[1], mn2 = smm[2];
    int max1 = smm[4] - mn1, max2 = smm[5] - mn2;

    #pragma unroll
    for (int s = 0; s < 4; ++s) {
        int i = t + s * 1024;
        smem[i] = make_comp2(b, base + i, qbuf, mn0, mn1, mn2, max1, max2, lmask, imask);
    }
    __syncthreads();
    for (int k = 2; k <= 4096; k <<= 1) {
        for (int j = k >> 1; j > 0; j >>= 1) {
            #pragma unroll
            for (int pp = 0; pp < 2; ++pp) {
                int p = t + pp * 1024;                      // pair idx [0,2048)
                int i = ((p & ~(j-1)) << 1) | (p & (j-1));
                int l = i | j;
                bool up = (((base + i) & k) == 0);
                unsigned long long a = smem[i], c = smem[l];
                if ((a > c) == up) { smem[i] = c; smem[l] = a; }
            }
            __syncthreads();
        }
    }
    unsigned long long* seg = comps + ((size_t)b << 15) + base;
    #pragma unroll
    for (int s = 0; s < 4; ++s) { int i = t + s*1024; seg[i] = smem[i]; }
}

// Fused phase-K kernel (K = C*4096): block bb loads its column GROUP
// (C columns, stride-4096), replays the register phase steps locally and
// keeps its own column (redundant loads, L2-trivial), then LDS-merges
// j=2048..1. Direction is uniform per block: (bb & C)==0 for both phase
// and merge since index bits < 12 can't affect (idx & K) for K>=8192.
// in != out (ping-pong) because other blocks concurrently write their columns.
template<int C>
__global__ __launch_bounds__(1024) void sort_phase_fused_kernel(
    const unsigned long long* __restrict__ in, unsigned long long* __restrict__ outc)
{
    __shared__ unsigned long long smem[4096];
    int blk = blockIdx.x;                       // 32 blocks
    int b = blk >> 3, bb = blk & 7;
    const int g0 = bb & ~(C - 1);
    const int sel = bb & (C - 1);
    const bool up = ((bb & C) == 0);
    const unsigned long long* inseg = in + ((size_t)b << 15);
    int t = threadIdx.x;
    #pragma unroll
    for (int s = 0; s < 4; ++s) {
        int low = t + s * 1024;
        unsigned long long e[C];
        #pragma unroll
        for (int mi = 0; mi < C; ++mi)
            e[mi] = inseg[low + ((g0 + mi) << 12)];
        #pragma unroll
        for (int JM = C >> 1; JM > 0; JM >>= 1) {
            #pragma unroll
            for (int mi = 0; mi < C; ++mi) {
                if ((mi & JM) == 0) {
                    unsigned long long a = e[mi], c2 = e[mi | JM];
                    if ((a > c2) == up) { e[mi] = c2; e[mi | JM] = a; }
                }
            }
        }
        unsigned long long keep = e[0];
        #pragma unroll
        for (int mi = 1; mi < C; ++mi) if (sel == mi) keep = e[mi];  // static idx only
        smem[low] = keep;
    }
    __syncthreads();
    for (int j = 2048; j > 0; j >>= 1) {
        #pragma unroll
        for (int pp = 0; pp < 2; ++pp) {
            int p = t + pp * 1024;
            int i = ((p & ~(j - 1)) << 1) | (p & (j - 1));
            int l = i | j;
            unsigned long long a = smem[i], c2 = smem[l];
            if ((a > c2) == up) { smem[i] = c2; smem[l] = a; }
        }
        __syncthreads();
    }
    unsigned long long* outseg = outc + ((size_t)b << 15) + bb * 4096;
    #pragma unroll
    for (int s = 0; s < 4; ++s) { int i = t + s * 1024; outseg[i] = smem[i]; }
}

// gather: 8 rows per wave. R6 lesson: the compiler FUSED the load/store
// loops down to VGPR_Count=16 (≈2 rows in flight, dependent chains, 2.3
// TB/s). Fix: asm memory fence between the loops forces all 8 loads to
// issue before the first store (true MLP; VGPR should rise to ~48).
// Output rows stored non-temporally (write-once, never re-read) so they
// don't evict the L3-warm token data we're still reading.
// R7 fix: NT store builtin needs a NATIVE vector type (ext_vector_type),
// not HIP's float4 class -> floatx4.
__global__ __launch_bounds__(256) void gather_kernel(
    const unsigned long long* __restrict__ comps,
    const float* __restrict__ lidar_tokens,
    const float* __restrict__ img_tokens,
    const unsigned char* __restrict__ lmask,
    const unsigned char* __restrict__ imask,
    float* __restrict__ out)
{
    int wave = threadIdx.x >> 6, lane = threadIdx.x & 63;
    int row0 = (blockIdx.x * 4 + wave) * 8;     // 8 consecutive rows, same batch (N_TOT%8==0)
    int b = row0 / N_TOT;
    int pos0 = row0 - b * N_TOT;
    unsigned long long carr = comps[((size_t)b << 15) + pos0 + (lane & 7)];
    int srcs[8];
    #pragma unroll
    for (int r = 0; r < 8; ++r)
        srcs[r] = (int)(__shfl(carr, r) & 0xFFFFu);
    floatx4 vals[8];
    #pragma unroll
    for (int r = 0; r < 8; ++r) {
        int s = srcs[r];
        const floatx4* p = (s < N_LIDAR)
            ? (const floatx4*)(lidar_tokens + ((size_t)b * N_LIDAR + s) * NC)
            : (const floatx4*)(img_tokens + ((size_t)b * N_IMG + (s - N_LIDAR)) * NC);
        vals[r] = p[lane];
    }
    asm volatile("" ::: "memory");   // keep all 8 loads issued before first store
    #pragma unroll
    for (int r = 0; r < 8; ++r)
        __builtin_nontemporal_store(vals[r],
            (floatx4*)(out + (size_t)(row0 + r) * NC) + lane);
    if (lane < 8) {
        int s = (int)(carr & 0xFFFFu);
        int row = row0 + lane;
        out[TOK_END + row] = (float)s;
        bool m = (s < N_LIDAR) ? (lmask[b * N_LIDAR + s] != 0)
                               : (imask[b * N_IMG + s - N_LIDAR] != 0);
        out[IDX_END + row] = m ? 1.0f : 0.0f;
    }
    if (row0 == 0 && lane == 0) {
        out[MSK_END]     = (float)N_LIDAR;
        out[MSK_END + 1] = 1.0f;
    }
}

extern "C" void kernel_launch(void* const* d_in, const int* in_sizes, int n_in,
                              void* d_out, int out_size, void* d_ws, size_t ws_size,
                              hipStream_t stream) {
    const float* lidar_tokens = (const float*)d_in[0];
    const float* lidar_coords = (const float*)d_in[1];
    const float* img_tokens   = (const float*)d_in[2];
    const float* img_kuvd     = (const float*)d_in[3];
    const float* Kmat         = (const float*)d_in[4];
    const float* Tmat         = (const float*)d_in[5];
    const float* postR        = (const float*)d_in[6];
    const float* postT        = (const float*)d_in[7];
    const unsigned char* lmask = (const unsigned char*)d_in[8];
    const unsigned char* imask = (const unsigned char*)d_in[9];
    float* out = (float*)d_out;

    char* ws = (char*)d_ws;
    unsigned long long* compsA = (unsigned long long*)(ws + WS_COMPSA_OFF);
    unsigned long long* compsB = (unsigned long long*)(ws + WS_COMPSB_OFF);
    int4* qbuf    = (int4*)(ws + WS_QBUF_OFF);      // aliases compsB (qbuf dead after local sort)
    int*  blockmm = (int*)(ws + WS_BMM_OFF);

    quant_kernel<<<(NB * N_TOT) / 256, 256, 0, stream>>>(
        lidar_coords, img_kuvd, Kmat, Tmat, postR, postT, qbuf, blockmm);

    sort_local_full_kernel<<<32, 1024, 0, stream>>>(qbuf, blockmm, lmask, imask, compsA);

    sort_phase_fused_kernel<2><<<32, 1024, 0, stream>>>(compsA, compsB);  // k=8192
    sort_phase_fused_kernel<4><<<32, 1024, 0, stream>>>(compsB, compsA);  // k=16384
    sort_phase_fused_kernel<8><<<32, 1024, 0, stream>>>(compsA, compsB);  // k=32768

    gather_kernel<<<(NB * N_TOT) / 32, 256, 0, stream>>>(
        compsB, lidar_tokens, img_tokens, lmask, imask, out);
}